// Round 1
// baseline (506.467 us; speedup 1.0000x reference)
//
#include <hip/hip_runtime.h>
#include <hip/hip_bf16.h>
#include <math.h>

#define BDIM 4096
#define DDIM 2048
#define PDIM 128
#define CDIM 10
#define TB   8192   // 2*B

// exp(cos/TEMP) with TEMP=0.5  ->  exp2(cos * 2/ln2)
#define EXP_SCALE 2.8853900817779268f
#define LAMBDA 0.2f
#define EPS 1e-8f

// ws layout (float index):
//  [0]            sup_acc (float)
//  [1]            flag (int: 1 => labels are int64-layout)
//  [16 .. 16+8192)        rowsum
//  [16+8192 .. 16+16384)  possum
//  [16400 .. )            phat [8192][128] f32

// ---------------- k0: zero accumulators ----------------
__global__ void k0_zero(float* __restrict__ ws_f) {
    int idx = blockIdx.x * 256 + threadIdx.x;
    if (idx < 16 + 2 * TB) ws_f[idx] = 0.0f;
}

// ---------------- kf: detect int64 label layout ----------------
__global__ void kf_flag(const int* __restrict__ y32, int* __restrict__ flag_out) {
    __shared__ int s_ok;
    if (threadIdx.x == 0) s_ok = 1;
    __syncthreads();
    int ok = 1;
    #pragma unroll
    for (int i = 0; i < 8; ++i) {
        int w = 2 * (threadIdx.x + 256 * i) + 1;   // odd words 1..4095
        if (y32[w] != 0) ok = 0;
    }
    if (!ok) atomicAnd(&s_ok, 0);
    __syncthreads();
    if (threadIdx.x == 0) *flag_out = s_ok;
}

// ---------------- k1: proj GEMM + row-normalize -> phat ----------------
// grid 256 x 256 threads. Each WG: 32 virtual rows x full 128 cols.
__global__ __launch_bounds__(256) void k1_proj(
    const float* __restrict__ xi, const float* __restrict__ xj,
    const float* __restrict__ Wp, float* __restrict__ phat)
{
    __shared__ float Xs[32][64];        // 8 KB
    __shared__ float Ws[64 * 128];      // 32 KB
    const int wg  = blockIdx.x;
    const int tid = threadIdx.x;
    const float* src = (wg < 128) ? xi : xj;
    const int row0 = (wg & 127) * 32;           // row within src matrix
    const int tr = tid >> 5, tc = tid & 31;     // 8 row-groups x 32 col-groups

    float acc[4][4] = {};

    for (int k0 = 0; k0 < DDIM; k0 += 64) {
        __syncthreads();
        // stage X tile: 32x64 floats, 8 per thread
        {
            int e = tid * 8;
            int r = e >> 6, c = e & 63;
            const float4* s4 = (const float4*)(src + (size_t)(row0 + r) * DDIM + k0 + c);
            *(float4*)&Xs[r][c]     = s4[0];
            *(float4*)&Xs[r][c + 4] = s4[1];
        }
        // stage W tile: rows k0..k0+63, all 128 cols (contiguous 8192 floats)
        {
            const float4* s4 = (const float4*)(Wp + (size_t)k0 * PDIM);
            float4* d4 = (float4*)Ws;
            #pragma unroll
            for (int i = 0; i < 8; ++i) d4[tid + 256 * i] = s4[tid + 256 * i];
        }
        __syncthreads();

        #pragma unroll 4
        for (int kk = 0; kk < 64; kk += 4) {
            float4 a[4], b[4];
            #pragma unroll
            for (int i = 0; i < 4; ++i) a[i] = *(const float4*)&Xs[tr * 4 + i][kk];
            #pragma unroll
            for (int q = 0; q < 4; ++q) b[q] = *(const float4*)&Ws[(kk + q) * 128 + tc * 4];
            #pragma unroll
            for (int q = 0; q < 4; ++q) {
                float4 bq = b[q];
                #pragma unroll
                for (int i = 0; i < 4; ++i) {
                    float av = (q == 0) ? a[i].x : (q == 1) ? a[i].y : (q == 2) ? a[i].z : a[i].w;
                    acc[i][0] = fmaf(av, bq.x, acc[i][0]);
                    acc[i][1] = fmaf(av, bq.y, acc[i][1]);
                    acc[i][2] = fmaf(av, bq.z, acc[i][2]);
                    acc[i][3] = fmaf(av, bq.w, acc[i][3]);
                }
            }
        }
    }

    // row sum-of-squares reduce across the 32 threads (tc) sharing each row
    #pragma unroll
    for (int i = 0; i < 4; ++i) {
        float s = acc[i][0] * acc[i][0] + acc[i][1] * acc[i][1]
                + acc[i][2] * acc[i][2] + acc[i][3] * acc[i][3];
        #pragma unroll
        for (int m = 16; m >= 1; m >>= 1) s += __shfl_xor(s, m, 32);
        float rn = rsqrtf(s);
        float4 ph;
        ph.x = acc[i][0] * rn; ph.y = acc[i][1] * rn;
        ph.z = acc[i][2] * rn; ph.w = acc[i][3] * rn;
        int vrow = wg * 32 + tr * 4 + i;   // global virtual row 0..8191
        *(float4*)&phat[(size_t)vrow * PDIM + tc * 4] = ph;
    }
}

// ---------------- k2: classifier digits + CE ----------------
// grid 2048 x 256 threads; one wave (64 lanes) per virtual row, 4 rows/WG.
__global__ __launch_bounds__(256) void k2_ce(
    const float* __restrict__ xi, const float* __restrict__ xj,
    const float* __restrict__ Wc, const int* __restrict__ y,
    const int* __restrict__ flag_p, float* __restrict__ sup_acc)
{
    __shared__ float WT[CDIM][DDIM];    // W_cls transposed, 80 KB
    const int tid = threadIdx.x;
    #pragma unroll
    for (int i = 0; i < 80; ++i) {
        int idx = tid + 256 * i;        // < 20480
        int k = idx / 10, c = idx - k * 10;
        WT[c][k] = Wc[idx];
    }
    __syncthreads();

    const int wid = tid >> 6, lane = tid & 63;
    const int r = blockIdx.x * 4 + wid;
    const float* src = (r < BDIM) ? (xi + (size_t)r * DDIM)
                                  : (xj + (size_t)(r - BDIM) * DDIM);
    float d[CDIM] = {};
    for (int t = 0; t < 8; ++t) {
        int k0 = t * 256 + lane * 4;
        float4 xv = *(const float4*)(src + k0);
        #pragma unroll
        for (int c = 0; c < CDIM; ++c) {
            float4 wv = *(const float4*)&WT[c][k0];
            d[c] += xv.x * wv.x + xv.y * wv.y + xv.z * wv.z + xv.w * wv.w;
        }
    }
    #pragma unroll
    for (int c = 0; c < CDIM; ++c) {
        float v = d[c];
        #pragma unroll
        for (int m = 32; m >= 1; m >>= 1) v += __shfl_xor(v, m, 64);
        d[c] = v;
    }
    if (lane == 0) {
        int idx = r & (BDIM - 1);
        int label = (*flag_p) ? y[2 * idx] : y[idx];
        float m = -1e30f;
        #pragma unroll
        for (int c = 0; c < CDIM; ++c) m = fmaxf(m, d[c]);
        float s = 0.0f;
        #pragma unroll
        for (int c = 0; c < CDIM; ++c) s += __expf(d[c] - m);
        float lse = m + __logf(s);
        float dl = 0.0f;
        #pragma unroll
        for (int c = 0; c < CDIM; ++c) dl = (c == label) ? d[c] : dl;
        atomicAdd(sup_acc, (lse - dl) * (1.0f / BDIM));
    }
}

// ---------------- k3: Gram row-sum + positive-pair gather ----------------
// grid 256 x 512 threads. WG = (I-block of 64 rows) x (half of J range).
__global__ __launch_bounds__(512) void k3_gram(
    const float* __restrict__ phat,
    float* __restrict__ rowsum, float* __restrict__ possum)
{
    __shared__ float As[64 * 132];      // padded stride 132 -> broadcast-friendly
    __shared__ float Bs[128 * 128];     // skewed layout, conflict-free reads
    const int tid = threadIdx.x;
    const int wg  = blockIdx.x;
    const int I0 = (wg >> 1) * 64;
    const int J0 = (wg & 1) * 4096;

    // stage A once: 64x128 floats
    #pragma unroll
    for (int i = 0; i < 4; ++i) {
        int ci = tid + 512 * i;             // float4 chunk id, 0..2047
        int row = ci >> 5, kc = ci & 31;
        float4 v = *(const float4*)(phat + (size_t)(I0 + row) * PDIM + kc * 4);
        *(float4*)&As[row * 132 + kc * 4] = v;
    }

    const int tr = tid >> 5, tc = tid & 31;   // 16 row-groups x 32 col-groups
    float rs[4] = {0, 0, 0, 0}, ps[4] = {0, 0, 0, 0};

    for (int jb = 0; jb < 32; ++jb) {
        const int Jb = J0 + jb * 128;
        __syncthreads();
        // stage B block with skew: dword pos = (k + 4*(row>>2)) & 127
        #pragma unroll
        for (int i = 0; i < 8; ++i) {
            int ci = tid + 512 * i;         // 0..4095
            int row = ci >> 5, k = (ci & 31) * 4;
            float4 v = *(const float4*)(phat + (size_t)(Jb + row) * PDIM + k);
            int pos = (k + 4 * (row >> 2)) & 127;
            *(float4*)&Bs[row * 128 + pos] = v;
        }
        __syncthreads();

        float acc[4][4] = {};
        #pragma unroll 4
        for (int kk = 0; kk < 128; kk += 4) {
            float4 a[4], b[4];
            #pragma unroll
            for (int i = 0; i < 4; ++i) a[i] = *(const float4*)&As[(tr * 4 + i) * 132 + kk];
            int bp = (kk + 4 * tc) & 127;
            #pragma unroll
            for (int j = 0; j < 4; ++j) b[j] = *(const float4*)&Bs[(tc * 4 + j) * 128 + bp];
            #pragma unroll
            for (int i = 0; i < 4; ++i) {
                #pragma unroll
                for (int j = 0; j < 4; ++j) {
                    acc[i][j] = fmaf(a[i].x, b[j].x, acc[i][j]);
                    acc[i][j] = fmaf(a[i].y, b[j].y, acc[i][j]);
                    acc[i][j] = fmaf(a[i].z, b[j].z, acc[i][j]);
                    acc[i][j] = fmaf(a[i].w, b[j].w, acc[i][j]);
                }
            }
        }

        // epilogue: exp, mask diagonal, gather positive pair
        #pragma unroll
        for (int i = 0; i < 4; ++i) {
            int gi = I0 + tr * 4 + i;
            int partner = gi ^ BDIM;
            #pragma unroll
            for (int j = 0; j < 4; ++j) {
                int gj = Jb + tc * 4 + j;
                float e = exp2f(acc[i][j] * EXP_SCALE);
                rs[i] += (gi == gj) ? 0.0f : e;
                ps[i] += (gj == partner) ? e : 0.0f;
            }
        }
    }

    // reduce over the 32 col-group threads sharing each row
    #pragma unroll
    for (int i = 0; i < 4; ++i) {
        float r = rs[i], p = ps[i];
        #pragma unroll
        for (int m = 16; m >= 1; m >>= 1) {
            r += __shfl_xor(r, m, 32);
            p += __shfl_xor(p, m, 32);
        }
        if (tc == 0) {
            atomicAdd(&rowsum[I0 + tr * 4 + i], r);
            atomicAdd(&possum[I0 + tr * 4 + i], p);
        }
    }
}

// ---------------- k4: final reduction ----------------
__global__ __launch_bounds__(256) void k4_final(
    const float* __restrict__ rowsum, const float* __restrict__ possum,
    const float* __restrict__ sup_acc, float* __restrict__ out)
{
    __shared__ float red[4];
    const int tid = threadIdx.x;
    float s = 0.0f;
    #pragma unroll
    for (int i = 0; i < 32; ++i) {
        int r = tid + 256 * i;
        s += -__logf(possum[r] / rowsum[r] + EPS);
    }
    #pragma unroll
    for (int m = 32; m >= 1; m >>= 1) s += __shfl_xor(s, m, 64);
    if ((tid & 63) == 0) red[tid >> 6] = s;
    __syncthreads();
    if (tid == 0) {
        float tot = red[0] + red[1] + red[2] + red[3];
        out[0] = tot * (1.0f / TB) + LAMBDA * sup_acc[0];
    }
}

extern "C" void kernel_launch(void* const* d_in, const int* in_sizes, int n_in,
                              void* d_out, int out_size, void* d_ws, size_t ws_size,
                              hipStream_t stream) {
    const float* xi = (const float*)d_in[1];
    const float* xj = (const float*)d_in[2];
    const int*   y  = (const int*)d_in[3];
    const float* Wp = (const float*)d_in[4];
    const float* Wc = (const float*)d_in[5];
    float* out  = (float*)d_out;

    float* ws_f   = (float*)d_ws;
    float* sup    = ws_f;
    int*   flag   = (int*)(ws_f + 1);
    float* rowsum = ws_f + 16;
    float* possum = ws_f + 16 + TB;
    float* phat   = ws_f + 16 + 2 * TB;

    k0_zero<<<(16 + 2 * TB + 255) / 256, 256, 0, stream>>>(ws_f);
    kf_flag<<<1, 256, 0, stream>>>(y, flag);
    k1_proj<<<256, 256, 0, stream>>>(xi, xj, Wp, phat);
    k2_ce<<<2048, 256, 0, stream>>>(xi, xj, Wc, y, flag, sup);
    k3_gram<<<256, 512, 0, stream>>>(phat, rowsum, possum);
    k4_final<<<1, 256, 0, stream>>>(rowsum, possum, sup, out);
}

// Round 2
// 273.725 us; speedup vs baseline: 1.8503x; 1.8503x over previous
//
#include <hip/hip_runtime.h>
#include <hip/hip_bf16.h>
#include <math.h>

#define BDIM 4096
#define DDIM 2048
#define PDIM 128
#define CDIM 10
#define TB   8192   // 2*B

// exp(cos/TEMP) with TEMP=0.5  ->  exp2(cos * 2/ln2)
#define EXP_SCALE 2.8853900817779268f
#define LAMBDA 0.2f
#define EPS 1e-8f

typedef __bf16 bfv8 __attribute__((ext_vector_type(8)));
typedef float  fv4  __attribute__((ext_vector_type(4)));

__device__ __forceinline__ unsigned short f2bf(float f) {
    unsigned int u = __float_as_uint(f);
    u += 0x7FFFu + ((u >> 16) & 1u);      // round-to-nearest-even
    return (unsigned short)(u >> 16);
}

// ws layout (float index):
//  [0]                    sup_acc
//  [1]                    flag (int)
//  [16 .. 16+8192)        rowsum
//  [16+8192 .. 16+16384)  possum
//  [16400 .. )            phat [8192][128] bf16 (2 MB)

// ---------------- k0: zero accumulators ----------------
__global__ void k0_zero(float* __restrict__ ws_f) {
    int idx = blockIdx.x * 256 + threadIdx.x;
    if (idx < 16 + 2 * TB) ws_f[idx] = 0.0f;
}

// ---------------- kf: detect int64 label layout ----------------
__global__ void kf_flag(const int* __restrict__ y32, int* __restrict__ flag_out) {
    __shared__ int s_ok;
    if (threadIdx.x == 0) s_ok = 1;
    __syncthreads();
    int ok = 1;
    #pragma unroll
    for (int i = 0; i < 8; ++i) {
        int w = 2 * (threadIdx.x + 256 * i) + 1;   // odd words 1..4095
        if (y32[w] != 0) ok = 0;
    }
    if (!ok) atomicAnd(&s_ok, 0);
    __syncthreads();
    if (threadIdx.x == 0) *flag_out = s_ok;
}

// ---------------- k1: proj GEMM + row-normalize -> phat (bf16) ----------------
// grid 256 x 256 threads. Each WG: 32 virtual rows x full 128 cols.
__global__ __launch_bounds__(256) void k1_proj(
    const float* __restrict__ xi, const float* __restrict__ xj,
    const float* __restrict__ Wp, unsigned short* __restrict__ phat)
{
    __shared__ float Xs[32][64];        // 8 KB
    __shared__ float Ws[64 * 128];      // 32 KB
    const int wg  = blockIdx.x;
    const int tid = threadIdx.x;
    const float* src = (wg < 128) ? xi : xj;
    const int row0 = (wg & 127) * 32;
    const int tr = tid >> 5, tc = tid & 31;

    float acc[4][4] = {};

    for (int k0 = 0; k0 < DDIM; k0 += 64) {
        __syncthreads();
        {
            int e = tid * 8;
            int r = e >> 6, c = e & 63;
            const float4* s4 = (const float4*)(src + (size_t)(row0 + r) * DDIM + k0 + c);
            *(float4*)&Xs[r][c]     = s4[0];
            *(float4*)&Xs[r][c + 4] = s4[1];
        }
        {
            const float4* s4 = (const float4*)(Wp + (size_t)k0 * PDIM);
            float4* d4 = (float4*)Ws;
            #pragma unroll
            for (int i = 0; i < 8; ++i) d4[tid + 256 * i] = s4[tid + 256 * i];
        }
        __syncthreads();

        #pragma unroll 4
        for (int kk = 0; kk < 64; kk += 4) {
            float4 a[4], b[4];
            #pragma unroll
            for (int i = 0; i < 4; ++i) a[i] = *(const float4*)&Xs[tr * 4 + i][kk];
            #pragma unroll
            for (int q = 0; q < 4; ++q) b[q] = *(const float4*)&Ws[(kk + q) * 128 + tc * 4];
            #pragma unroll
            for (int q = 0; q < 4; ++q) {
                float4 bq = b[q];
                #pragma unroll
                for (int i = 0; i < 4; ++i) {
                    float av = (q == 0) ? a[i].x : (q == 1) ? a[i].y : (q == 2) ? a[i].z : a[i].w;
                    acc[i][0] = fmaf(av, bq.x, acc[i][0]);
                    acc[i][1] = fmaf(av, bq.y, acc[i][1]);
                    acc[i][2] = fmaf(av, bq.z, acc[i][2]);
                    acc[i][3] = fmaf(av, bq.w, acc[i][3]);
                }
            }
        }
    }

    #pragma unroll
    for (int i = 0; i < 4; ++i) {
        float s = acc[i][0] * acc[i][0] + acc[i][1] * acc[i][1]
                + acc[i][2] * acc[i][2] + acc[i][3] * acc[i][3];
        #pragma unroll
        for (int m = 16; m >= 1; m >>= 1) s += __shfl_xor(s, m, 32);
        float rn = rsqrtf(s);
        ushort4 pk;
        pk.x = f2bf(acc[i][0] * rn); pk.y = f2bf(acc[i][1] * rn);
        pk.z = f2bf(acc[i][2] * rn); pk.w = f2bf(acc[i][3] * rn);
        int vrow = wg * 32 + tr * 4 + i;
        *(ushort4*)&phat[(size_t)vrow * PDIM + tc * 4] = pk;
    }
}

// ---------------- k2: classifier digits + CE ----------------
__global__ __launch_bounds__(256) void k2_ce(
    const float* __restrict__ xi, const float* __restrict__ xj,
    const float* __restrict__ Wc, const int* __restrict__ y,
    const int* __restrict__ flag_p, float* __restrict__ sup_acc)
{
    __shared__ float WT[CDIM][DDIM];    // 80 KB
    const int tid = threadIdx.x;
    #pragma unroll
    for (int i = 0; i < 80; ++i) {
        int idx = tid + 256 * i;
        int k = idx / 10, c = idx - k * 10;
        WT[c][k] = Wc[idx];
    }
    __syncthreads();

    const int wid = tid >> 6, lane = tid & 63;
    const int r = blockIdx.x * 4 + wid;
    const float* src = (r < BDIM) ? (xi + (size_t)r * DDIM)
                                  : (xj + (size_t)(r - BDIM) * DDIM);
    float d[CDIM] = {};
    for (int t = 0; t < 8; ++t) {
        int k0 = t * 256 + lane * 4;
        float4 xv = *(const float4*)(src + k0);
        #pragma unroll
        for (int c = 0; c < CDIM; ++c) {
            float4 wv = *(const float4*)&WT[c][k0];
            d[c] += xv.x * wv.x + xv.y * wv.y + xv.z * wv.z + xv.w * wv.w;
        }
    }
    #pragma unroll
    for (int c = 0; c < CDIM; ++c) {
        float v = d[c];
        #pragma unroll
        for (int m = 32; m >= 1; m >>= 1) v += __shfl_xor(v, m, 64);
        d[c] = v;
    }
    if (lane == 0) {
        int idx = r & (BDIM - 1);
        int label = (*flag_p) ? y[2 * idx] : y[idx];
        float m = -1e30f;
        #pragma unroll
        for (int c = 0; c < CDIM; ++c) m = fmaxf(m, d[c]);
        float s = 0.0f;
        #pragma unroll
        for (int c = 0; c < CDIM; ++c) s += __expf(d[c] - m);
        float lse = m + __logf(s);
        float dl = 0.0f;
        #pragma unroll
        for (int c = 0; c < CDIM; ++c) dl = (c == label) ? d[c] : dl;
        atomicAdd(sup_acc, (lse - dl) * (1.0f / BDIM));
    }
}

// ---------------- k3: Gram row-sum via bf16 MFMA (upper-triangle tiles) ----
// 2080 blocks x 256 threads. Tile 128x128, 4 waves (2x2), wave-tile 64x64.
// Fragments load straight from global (phat is 2 MB, L2-resident):
// both A and B fragments of P.P^T are contiguous 16B row-reads of phat.
__global__ __launch_bounds__(256) void k3_gram_mfma(
    const __bf16* __restrict__ ph,
    float* __restrict__ rowsum, float* __restrict__ possum)
{
    __shared__ float srs[256];   // [0:128) I-block row partials, [128:256) J-block
    __shared__ float sps[256];
    const int tid = threadIdx.x;

    // decode upper-triangle tile (ti <= tj), 64x64 tile grid
    int t = blockIdx.x;
    int ti = 0;
    while (t >= 64 - ti) { t -= 64 - ti; ++ti; }
    const int tj = ti + t;
    const int I0 = ti * 128, J0 = tj * 128;
    const bool diag    = (ti == tj);
    const bool partner = (tj == ti + 32);   // J-block holds i^4096 partners

    srs[tid] = 0.0f;
    sps[tid] = 0.0f;
    __syncthreads();

    const int wid = tid >> 6, lane = tid & 63;
    const int wr = wid >> 1, wc = wid & 1;
    const int l15 = lane & 15, lg = lane >> 4;

    const int arow = I0 + wr * 64 + l15;    // + m*16
    const int brow = J0 + wc * 64 + l15;    // + n*16
    const int kb   = lg * 8;

    fv4 acc[4][4] = {};
    #pragma unroll
    for (int ks = 0; ks < 4; ++ks) {
        bfv8 a[4], b[4];
        #pragma unroll
        for (int m = 0; m < 4; ++m)
            a[m] = *(const bfv8*)(ph + (size_t)(arow + m * 16) * PDIM + ks * 32 + kb);
        #pragma unroll
        for (int n = 0; n < 4; ++n)
            b[n] = *(const bfv8*)(ph + (size_t)(brow + n * 16) * PDIM + ks * 32 + kb);
        #pragma unroll
        for (int m = 0; m < 4; ++m)
            #pragma unroll
            for (int n = 0; n < 4; ++n)
                acc[m][n] = __builtin_amdgcn_mfma_f32_16x16x32_bf16(a[m], b[n], acc[m][n], 0, 0, 0);
    }

    // epilogue: e = exp2(c*scale); diag-mask; row sums + col sums + positives
    // C/D layout: row_in_frag = lg*4 + r, col_in_frag = l15
    float cs_l[4] = {0, 0, 0, 0};            // per-n col partials (sum over m,r)
    float cp_l[4] = {0, 0, 0, 0};
    #pragma unroll
    for (int m = 0; m < 4; ++m) {
        float rs_l[4] = {0, 0, 0, 0};        // per-r row partials (sum over n)
        float ps_l[4] = {0, 0, 0, 0};
        #pragma unroll
        for (int n = 0; n < 4; ++n) {
            #pragma unroll
            for (int r = 0; r < 4; ++r) {
                const int ri = wr * 64 + m * 16 + lg * 4 + r;  // row in tile
                const int cj = wc * 64 + n * 16 + l15;         // col in tile
                float e = exp2f(acc[m][n][r] * EXP_SCALE);
                if (diag && ri == cj) e = 0.0f;
                const bool isp = partner && (ri == cj);
                rs_l[r] += e;
                cs_l[n] += e;
                if (isp) { ps_l[r] += e; cp_l[n] += e; }
            }
        }
        // reduce rows across the 16 lanes (l15) sharing each row
        #pragma unroll
        for (int r = 0; r < 4; ++r) {
            float v = rs_l[r], p = ps_l[r];
            #pragma unroll
            for (int msk = 8; msk >= 1; msk >>= 1) {
                v += __shfl_xor(v, msk, 64);
                p += __shfl_xor(p, msk, 64);
            }
            if (l15 == 0) {
                atomicAdd(&srs[wr * 64 + m * 16 + lg * 4 + r], v);
                if (partner) atomicAdd(&sps[wr * 64 + m * 16 + lg * 4 + r], p);
            }
        }
    }
    // reduce cols across the 4 lane-groups (lg) sharing each col
    if (!diag) {
        #pragma unroll
        for (int n = 0; n < 4; ++n) {
            float v = cs_l[n], p = cp_l[n];
            v += __shfl_xor(v, 16, 64); v += __shfl_xor(v, 32, 64);
            p += __shfl_xor(p, 16, 64); p += __shfl_xor(p, 32, 64);
            if (lg == 0) {
                atomicAdd(&srs[128 + wc * 64 + n * 16 + l15], v);
                if (partner) atomicAdd(&sps[128 + wc * 64 + n * 16 + l15], p);
            }
        }
    }
    __syncthreads();

    // one global atomic per row per side
    if (tid < 128) {
        atomicAdd(&rowsum[I0 + tid], srs[tid]);
        if (partner) atomicAdd(&possum[I0 + tid], sps[tid]);
    } else if (!diag) {
        atomicAdd(&rowsum[J0 + tid - 128], srs[tid]);
        if (partner) atomicAdd(&possum[J0 + tid - 128], sps[tid]);
    }
}

// ---------------- k4: final reduction ----------------
__global__ __launch_bounds__(256) void k4_final(
    const float* __restrict__ rowsum, const float* __restrict__ possum,
    const float* __restrict__ sup_acc, float* __restrict__ out)
{
    __shared__ float red[4];
    const int tid = threadIdx.x;
    float s = 0.0f;
    #pragma unroll
    for (int i = 0; i < 32; ++i) {
        int r = tid + 256 * i;
        s += -__logf(possum[r] / rowsum[r] + EPS);
    }
    #pragma unroll
    for (int m = 32; m >= 1; m >>= 1) s += __shfl_xor(s, m, 64);
    if ((tid & 63) == 0) red[tid >> 6] = s;
    __syncthreads();
    if (tid == 0) {
        float tot = red[0] + red[1] + red[2] + red[3];
        out[0] = tot * (1.0f / TB) + LAMBDA * sup_acc[0];
    }
}

extern "C" void kernel_launch(void* const* d_in, const int* in_sizes, int n_in,
                              void* d_out, int out_size, void* d_ws, size_t ws_size,
                              hipStream_t stream) {
    const float* xi = (const float*)d_in[1];
    const float* xj = (const float*)d_in[2];
    const int*   y  = (const int*)d_in[3];
    const float* Wp = (const float*)d_in[4];
    const float* Wc = (const float*)d_in[5];
    float* out  = (float*)d_out;

    float* ws_f   = (float*)d_ws;
    float* sup    = ws_f;
    int*   flag   = (int*)(ws_f + 1);
    float* rowsum = ws_f + 16;
    float* possum = ws_f + 16 + TB;
    unsigned short* phat_u = (unsigned short*)(ws_f + 16 + 2 * TB);

    k0_zero<<<(16 + 2 * TB + 255) / 256, 256, 0, stream>>>(ws_f);
    kf_flag<<<1, 256, 0, stream>>>(y, flag);
    k1_proj<<<256, 256, 0, stream>>>(xi, xj, Wp, phat_u);
    k2_ce<<<2048, 256, 0, stream>>>(xi, xj, Wc, y, flag, sup);
    k3_gram_mfma<<<2080, 256, 0, stream>>>((const __bf16*)phat_u, rowsum, possum);
    k4_final<<<1, 256, 0, stream>>>(rowsum, possum, sup, out);
}

// Round 3
// 126.671 us; speedup vs baseline: 3.9983x; 2.1609x over previous
//
#include <hip/hip_runtime.h>
#include <hip/hip_bf16.h>
#include <math.h>

#define BDIM 4096
#define DDIM 2048
#define PDIM 128
#define CDIM 10
#define TB   8192   // 2*B

// exp(cos/TEMP) with TEMP=0.5  ->  exp2(cos * 2/ln2)
#define EXP_SCALE 2.8853900817779268f
#define LAMBDA 0.2f
#define EPS 1e-8f

typedef __bf16 bfv8 __attribute__((ext_vector_type(8)));
typedef float  fv4  __attribute__((ext_vector_type(4)));
typedef unsigned short usv8 __attribute__((ext_vector_type(8)));

__device__ __forceinline__ unsigned short f2bf(float f) {
    unsigned int u = __float_as_uint(f);
    u += 0x7FFFu + ((u >> 16) & 1u);      // round-to-nearest-even
    return (unsigned short)(u >> 16);
}

// ws layout (float index):
//  [0]                    sup_acc
//  [1]                    flag (int)
//  [16 .. 16+8192)        rowsum
//  [16+8192 .. 16+16384)  possum
//  [16400 ..)             phat  [8192][128] bf16   (524288 floats)
//  [540688 ..)            WpT   [128][2048] bf16   (131072 floats)
//  [671760 ..)            WcT   [16][2048]  bf16   (16384 floats)

// ---------------- k0: zero accumulators ----------------
__global__ void k0_zero(float* __restrict__ ws_f) {
    int idx = blockIdx.x * 256 + threadIdx.x;
    if (idx < 16 + 2 * TB) ws_f[idx] = 0.0f;
}

// ---------------- kf: detect int64 label layout ----------------
__global__ void kf_flag(const int* __restrict__ y32, int* __restrict__ flag_out) {
    __shared__ int s_ok;
    if (threadIdx.x == 0) s_ok = 1;
    __syncthreads();
    int ok = 1;
    #pragma unroll
    for (int i = 0; i < 8; ++i) {
        int w = 2 * (threadIdx.x + 256 * i) + 1;   // odd words 1..4095
        if (y32[w] != 0) ok = 0;
    }
    if (!ok) atomicAnd(&s_ok, 0);
    __syncthreads();
    if (threadIdx.x == 0) *flag_out = s_ok;
}

// ---------------- kw: build bf16 transposed weights ----------------
__global__ __launch_bounds__(256) void kw_prep(
    const float* __restrict__ Wp, const float* __restrict__ Wc,
    unsigned short* __restrict__ WpT, unsigned short* __restrict__ WcT)
{
    int idx = blockIdx.x * 256 + threadIdx.x;
    if (idx < PDIM * DDIM) {
        int p = idx >> 11, k = idx & 2047;
        WpT[idx] = f2bf(Wp[(size_t)k * PDIM + p]);
    } else {
        int j = idx - PDIM * DDIM;          // < 16*2048
        int c = j >> 11, k = j & 2047;
        WcT[j] = (c < CDIM) ? f2bf(Wc[(size_t)k * CDIM + c]) : (unsigned short)0;
    }
}

// ---------------- k13: fused proj-GEMM + normalize + digits + CE -----------
// 512 blocks x 256 thr (4 waves). Block owns 16 rows; wave w owns K-chunk
// [w*512,(w+1)*512). A-frags converted fp32->bf16 in-register (x read ONCE).
// 9 MFMAs per K-step: 8 proj n-groups + 1 digits.
__global__ __launch_bounds__(256) void k13_fused(
    const float* __restrict__ xi, const float* __restrict__ xj,
    const __bf16* __restrict__ WpT, const __bf16* __restrict__ WcT,
    const int* __restrict__ y, const int* __restrict__ flag_p,
    unsigned short* __restrict__ phat, float* __restrict__ sup_acc)
{
    __shared__ float sproj[4][16][128];   // 32 KB
    __shared__ float sdig[4][16][16];     // 4 KB
    __shared__ float sce[16];

    const int tid = threadIdx.x;
    const int wv = tid >> 6, lane = tid & 63;
    const int l15 = lane & 15, lg = lane >> 4;
    const int R0 = blockIdx.x * 16;
    const float* src = (R0 < BDIM) ? (xi + (size_t)R0 * DDIM)
                                   : (xj + (size_t)(R0 - BDIM) * DDIM);
    const int Kb = wv * 512;

    fv4 accp[8] = {};
    fv4 accd = {};

    #pragma unroll 2
    for (int ks = 0; ks < 16; ++ks) {
        const int k = Kb + ks * 32 + lg * 8;
        const float* xp = src + (size_t)l15 * DDIM + k;
        float4 x0 = *(const float4*)xp;
        float4 x1 = *(const float4*)(xp + 4);
        usv8 au;
        au[0] = f2bf(x0.x); au[1] = f2bf(x0.y); au[2] = f2bf(x0.z); au[3] = f2bf(x0.w);
        au[4] = f2bf(x1.x); au[5] = f2bf(x1.y); au[6] = f2bf(x1.z); au[7] = f2bf(x1.w);
        bfv8 a = __builtin_bit_cast(bfv8, au);

        #pragma unroll
        for (int n = 0; n < 8; ++n) {
            bfv8 b = *(const bfv8*)(WpT + (size_t)(n * 16 + l15) * DDIM + k);
            accp[n] = __builtin_amdgcn_mfma_f32_16x16x32_bf16(a, b, accp[n], 0, 0, 0);
        }
        bfv8 bc = *(const bfv8*)(WcT + (size_t)l15 * DDIM + k);
        accd = __builtin_amdgcn_mfma_f32_16x16x32_bf16(a, bc, accd, 0, 0, 0);
    }

    // scatter partials to LDS  (C layout: row=lg*4+r, col=l15)
    #pragma unroll
    for (int n = 0; n < 8; ++n)
        #pragma unroll
        for (int r = 0; r < 4; ++r)
            sproj[wv][lg * 4 + r][n * 16 + l15] = accp[n][r];
    #pragma unroll
    for (int r = 0; r < 4; ++r)
        sdig[wv][lg * 4 + r][l15] = accd[r];
    __syncthreads();

    // ---- proj: reduce 4 K-partials, rsqrt-normalize, write bf16 phat ----
    {
        const int row = tid >> 4;            // 0..15
        const int cg  = (tid & 15) * 8;      // 8 cols per thread
        fv4 p0 = {}, p1 = {};
        #pragma unroll
        for (int w = 0; w < 4; ++w) {
            p0 += *(const fv4*)&sproj[w][row][cg];
            p1 += *(const fv4*)&sproj[w][row][cg + 4];
        }
        float ssq = p0[0]*p0[0] + p0[1]*p0[1] + p0[2]*p0[2] + p0[3]*p0[3]
                  + p1[0]*p1[0] + p1[1]*p1[1] + p1[2]*p1[2] + p1[3]*p1[3];
        #pragma unroll
        for (int m = 8; m >= 1; m >>= 1) ssq += __shfl_xor(ssq, m, 64);
        float rn = rsqrtf(ssq);
        usv8 pk;
        pk[0] = f2bf(p0[0]*rn); pk[1] = f2bf(p0[1]*rn);
        pk[2] = f2bf(p0[2]*rn); pk[3] = f2bf(p0[3]*rn);
        pk[4] = f2bf(p1[0]*rn); pk[5] = f2bf(p1[1]*rn);
        pk[6] = f2bf(p1[2]*rn); pk[7] = f2bf(p1[3]*rn);
        *(usv8*)&phat[(size_t)(R0 + row) * PDIM + cg] = pk;
    }

    // ---- digits: reduce, CE via 16-lane shuffles ----
    {
        const int drow = tid >> 4;           // 0..15
        const int dc   = tid & 15;           // 0..15 (cols 10..15 are zero-pad)
        float d = 0.0f;
        #pragma unroll
        for (int w = 0; w < 4; ++w) d += sdig[w][drow][dc];
        float dv = (dc < CDIM) ? d : -1e30f;
        float mx = dv;
        #pragma unroll
        for (int m = 8; m >= 1; m >>= 1) mx = fmaxf(mx, __shfl_xor(mx, m, 64));
        float e = (dc < CDIM) ? __expf(d - mx) : 0.0f;
        float s = e;
        #pragma unroll
        for (int m = 8; m >= 1; m >>= 1) s += __shfl_xor(s, m, 64);
        const int rowg = R0 + drow;
        const int idx  = rowg & (BDIM - 1);
        const int label = (*flag_p) ? y[2 * idx] : y[idx];
        float dl = (dc == label) ? d : 0.0f;
        #pragma unroll
        for (int m = 8; m >= 1; m >>= 1) dl += __shfl_xor(dl, m, 64);
        if (dc == 0) sce[drow] = (mx + __logf(s)) - dl;
    }
    __syncthreads();
    if (tid == 0) {
        float t = 0.0f;
        #pragma unroll
        for (int r = 0; r < 16; ++r) t += sce[r];
        atomicAdd(sup_acc, t * (1.0f / BDIM));
    }
}

// ---------------- k3: Gram row-sum via bf16 MFMA (upper-triangle tiles) ----
__global__ __launch_bounds__(256) void k3_gram_mfma(
    const __bf16* __restrict__ ph,
    float* __restrict__ rowsum, float* __restrict__ possum)
{
    __shared__ float srs[256];
    __shared__ float sps[256];
    const int tid = threadIdx.x;

    int t = blockIdx.x;
    int ti = 0;
    while (t >= 64 - ti) { t -= 64 - ti; ++ti; }
    const int tj = ti + t;
    const int I0 = ti * 128, J0 = tj * 128;
    const bool diag    = (ti == tj);
    const bool partner = (tj == ti + 32);

    srs[tid] = 0.0f;
    sps[tid] = 0.0f;
    __syncthreads();

    const int wid = tid >> 6, lane = tid & 63;
    const int wr = wid >> 1, wc = wid & 1;
    const int l15 = lane & 15, lg = lane >> 4;

    const int arow = I0 + wr * 64 + l15;
    const int brow = J0 + wc * 64 + l15;
    const int kb   = lg * 8;

    fv4 acc[4][4] = {};
    #pragma unroll
    for (int ks = 0; ks < 4; ++ks) {
        bfv8 a[4], b[4];
        #pragma unroll
        for (int m = 0; m < 4; ++m)
            a[m] = *(const bfv8*)(ph + (size_t)(arow + m * 16) * PDIM + ks * 32 + kb);
        #pragma unroll
        for (int n = 0; n < 4; ++n)
            b[n] = *(const bfv8*)(ph + (size_t)(brow + n * 16) * PDIM + ks * 32 + kb);
        #pragma unroll
        for (int m = 0; m < 4; ++m)
            #pragma unroll
            for (int n = 0; n < 4; ++n)
                acc[m][n] = __builtin_amdgcn_mfma_f32_16x16x32_bf16(a[m], b[n], acc[m][n], 0, 0, 0);
    }

    float cs_l[4] = {0, 0, 0, 0};
    float cp_l[4] = {0, 0, 0, 0};
    #pragma unroll
    for (int m = 0; m < 4; ++m) {
        float rs_l[4] = {0, 0, 0, 0};
        float ps_l[4] = {0, 0, 0, 0};
        #pragma unroll
        for (int n = 0; n < 4; ++n) {
            #pragma unroll
            for (int r = 0; r < 4; ++r) {
                const int ri = wr * 64 + m * 16 + lg * 4 + r;
                const int cj = wc * 64 + n * 16 + l15;
                float e = exp2f(acc[m][n][r] * EXP_SCALE);
                if (diag && ri == cj) e = 0.0f;
                const bool isp = partner && (ri == cj);
                rs_l[r] += e;
                cs_l[n] += e;
                if (isp) { ps_l[r] += e; cp_l[n] += e; }
            }
        }
        #pragma unroll
        for (int r = 0; r < 4; ++r) {
            float v = rs_l[r], p = ps_l[r];
            #pragma unroll
            for (int msk = 8; msk >= 1; msk >>= 1) {
                v += __shfl_xor(v, msk, 64);
                p += __shfl_xor(p, msk, 64);
            }
            if (l15 == 0) {
                atomicAdd(&srs[wr * 64 + m * 16 + lg * 4 + r], v);
                if (partner) atomicAdd(&sps[wr * 64 + m * 16 + lg * 4 + r], p);
            }
        }
    }
    if (!diag) {
        #pragma unroll
        for (int n = 0; n < 4; ++n) {
            float v = cs_l[n], p = cp_l[n];
            v += __shfl_xor(v, 16, 64); v += __shfl_xor(v, 32, 64);
            p += __shfl_xor(p, 16, 64); p += __shfl_xor(p, 32, 64);
            if (lg == 0) {
                atomicAdd(&srs[128 + wc * 64 + n * 16 + l15], v);
                if (partner) atomicAdd(&sps[128 + wc * 64 + n * 16 + l15], p);
            }
        }
    }
    __syncthreads();

    if (tid < 128) {
        atomicAdd(&rowsum[I0 + tid], srs[tid]);
        if (partner) atomicAdd(&possum[I0 + tid], sps[tid]);
    } else if (!diag) {
        atomicAdd(&rowsum[J0 + tid - 128], srs[tid]);
        if (partner) atomicAdd(&possum[J0 + tid - 128], sps[tid]);
    }
}

// ---------------- k4: final reduction ----------------
__global__ __launch_bounds__(256) void k4_final(
    const float* __restrict__ rowsum, const float* __restrict__ possum,
    const float* __restrict__ sup_acc, float* __restrict__ out)
{
    __shared__ float red[4];
    const int tid = threadIdx.x;
    float s = 0.0f;
    #pragma unroll
    for (int i = 0; i < 32; ++i) {
        int r = tid + 256 * i;
        s += -__logf(possum[r] / rowsum[r] + EPS);
    }
    #pragma unroll
    for (int m = 32; m >= 1; m >>= 1) s += __shfl_xor(s, m, 64);
    if ((tid & 63) == 0) red[tid >> 6] = s;
    __syncthreads();
    if (tid == 0) {
        float tot = red[0] + red[1] + red[2] + red[3];
        out[0] = tot * (1.0f / TB) + LAMBDA * sup_acc[0];
    }
}

extern "C" void kernel_launch(void* const* d_in, const int* in_sizes, int n_in,
                              void* d_out, int out_size, void* d_ws, size_t ws_size,
                              hipStream_t stream) {
    const float* xi = (const float*)d_in[1];
    const float* xj = (const float*)d_in[2];
    const int*   y  = (const int*)d_in[3];
    const float* Wp = (const float*)d_in[4];
    const float* Wc = (const float*)d_in[5];
    float* out  = (float*)d_out;

    float* ws_f   = (float*)d_ws;
    float* sup    = ws_f;
    int*   flag   = (int*)(ws_f + 1);
    float* rowsum = ws_f + 16;
    float* possum = ws_f + 16 + TB;
    unsigned short* phat_u = (unsigned short*)(ws_f + 16 + 2 * TB);
    unsigned short* WpT_u  = (unsigned short*)(ws_f + 540688);
    unsigned short* WcT_u  = (unsigned short*)(ws_f + 671760);

    k0_zero<<<(16 + 2 * TB + 255) / 256, 256, 0, stream>>>(ws_f);
    kf_flag<<<1, 256, 0, stream>>>(y, flag);
    kw_prep<<<(PDIM * DDIM + 16 * DDIM) / 256, 256, 0, stream>>>(Wp, Wc, WpT_u, WcT_u);
    k13_fused<<<512, 256, 0, stream>>>(xi, xj, (const __bf16*)WpT_u, (const __bf16*)WcT_u,
                                       y, flag, phat_u, sup);
    k3_gram_mfma<<<2080, 256, 0, stream>>>((const __bf16*)phat_u, rowsum, possum);
    k4_final<<<1, 256, 0, stream>>>(rowsum, possum, sup, out);
}

// Round 4
// 101.624 us; speedup vs baseline: 4.9837x; 1.2465x over previous
//
#include <hip/hip_runtime.h>
#include <hip/hip_bf16.h>
#include <math.h>

#define BDIM 4096
#define DDIM 2048
#define PDIM 128
#define CDIM 10
#define TB   8192   // 2*B

// exp(cos/TEMP) with TEMP=0.5  ->  exp2(cos * 2/ln2)
#define EXP_SCALE 2.8853900817779268f
#define LAMBDA 0.2f
#define EPS 1e-8f

typedef __bf16 bfv8 __attribute__((ext_vector_type(8)));
typedef float  fv4  __attribute__((ext_vector_type(4)));
typedef unsigned short usv8 __attribute__((ext_vector_type(8)));

__device__ __forceinline__ unsigned short f2bf(float f) {
    unsigned int u = __float_as_uint(f);
    u += 0x7FFFu + ((u >> 16) & 1u);      // round-to-nearest-even
    return (unsigned short)(u >> 16);
}

// ws layout (float index):
//  [0]                    sup_acc
//  [1]                    flag (int)
//  [16 .. 16+8192)        rowsum
//  [16+8192 .. 16+16384)  possum
//  [16400 ..)             phat  [8192][128] bf16   (524288 floats)
//  [540688 ..)            WpT   [128][2048] bf16   (131072 floats)
//  [671760 ..)            WcT   [16][2048]  bf16   (16384 floats)

// ---------------- k0: zero accumulators (+ out) ----------------
__global__ void k0_zero(float* __restrict__ ws_f, float* __restrict__ out) {
    int idx = blockIdx.x * 256 + threadIdx.x;
    if (idx < 16 + 2 * TB) ws_f[idx] = 0.0f;
    if (idx == 0) out[0] = 0.0f;
}

// ---------------- kf: detect int64 label layout ----------------
__global__ void kf_flag(const int* __restrict__ y32, int* __restrict__ flag_out) {
    __shared__ int s_ok;
    if (threadIdx.x == 0) s_ok = 1;
    __syncthreads();
    int ok = 1;
    #pragma unroll
    for (int i = 0; i < 8; ++i) {
        int w = 2 * (threadIdx.x + 256 * i) + 1;   // odd words 1..4095
        if (y32[w] != 0) ok = 0;
    }
    if (!ok) atomicAnd(&s_ok, 0);
    __syncthreads();
    if (threadIdx.x == 0) *flag_out = s_ok;
}

// ---------------- kw: build bf16 transposed weights ----------------
__global__ __launch_bounds__(256) void kw_prep(
    const float* __restrict__ Wp, const float* __restrict__ Wc,
    unsigned short* __restrict__ WpT, unsigned short* __restrict__ WcT)
{
    int idx = blockIdx.x * 256 + threadIdx.x;
    if (idx < PDIM * DDIM) {
        int p = idx >> 11, k = idx & 2047;
        WpT[idx] = f2bf(Wp[(size_t)k * PDIM + p]);
    } else {
        int j = idx - PDIM * DDIM;          // < 16*2048
        int c = j >> 11, k = j & 2047;
        WcT[j] = (c < CDIM) ? f2bf(Wc[(size_t)k * CDIM + c]) : (unsigned short)0;
    }
}

// ---------------- k13: fused proj-GEMM + normalize + digits + CE -----------
// 512 blocks x 512 thr (8 waves). Block owns 16 rows; wave w owns K-chunk
// [w*256,(w+1)*256). Staged cross-wave reduction keeps static LDS < 64 KB.
__global__ __launch_bounds__(512) void k13_fused(
    const float* __restrict__ xi, const float* __restrict__ xj,
    const __bf16* __restrict__ WpT, const __bf16* __restrict__ WcT,
    const int* __restrict__ y, const int* __restrict__ flag_p,
    unsigned short* __restrict__ phat, float* __restrict__ sup_acc)
{
    __shared__ float sproj[4][16][132];   // 33.8 KB (4 merge slabs)
    __shared__ float sdig[8][16][16];     // 8 KB
    __shared__ float sce[16];

    const int tid = threadIdx.x;
    const int wv = tid >> 6, lane = tid & 63;
    const int l15 = lane & 15, lg = lane >> 4;
    const int R0 = blockIdx.x * 16;
    const float* src = (R0 < BDIM) ? (xi + (size_t)R0 * DDIM)
                                   : (xj + (size_t)(R0 - BDIM) * DDIM);
    const int Kb = wv * 256;

    fv4 accp[8] = {};
    fv4 accd = {};

    #pragma unroll 2
    for (int ks = 0; ks < 8; ++ks) {
        const int k = Kb + ks * 32 + lg * 8;
        const float* xp = src + (size_t)l15 * DDIM + k;
        float4 x0 = *(const float4*)xp;
        float4 x1 = *(const float4*)(xp + 4);
        usv8 au;
        au[0] = f2bf(x0.x); au[1] = f2bf(x0.y); au[2] = f2bf(x0.z); au[3] = f2bf(x0.w);
        au[4] = f2bf(x1.x); au[5] = f2bf(x1.y); au[6] = f2bf(x1.z); au[7] = f2bf(x1.w);
        bfv8 a = __builtin_bit_cast(bfv8, au);

        #pragma unroll
        for (int n = 0; n < 8; ++n) {
            bfv8 b = *(const bfv8*)(WpT + (size_t)(n * 16 + l15) * DDIM + k);
            accp[n] = __builtin_amdgcn_mfma_f32_16x16x32_bf16(a, b, accp[n], 0, 0, 0);
        }
        bfv8 bc = *(const bfv8*)(WcT + (size_t)l15 * DDIM + k);
        accd = __builtin_amdgcn_mfma_f32_16x16x32_bf16(a, bc, accd, 0, 0, 0);
    }

    // stage 1: waves 4..7 dump proj partials; everyone dumps digits
    if (wv >= 4) {
        #pragma unroll
        for (int n = 0; n < 8; ++n)
            #pragma unroll
            for (int r = 0; r < 4; ++r)
                sproj[wv - 4][lg * 4 + r][n * 16 + l15] = accp[n][r];
    }
    #pragma unroll
    for (int r = 0; r < 4; ++r)
        sdig[wv][lg * 4 + r][l15] = accd[r];
    __syncthreads();

    // stage 2: waves 0..3 merge partner slab into regs, dump merged
    if (wv < 4) {
        #pragma unroll
        for (int n = 0; n < 8; ++n)
            #pragma unroll
            for (int r = 0; r < 4; ++r)
                accp[n][r] += sproj[wv][lg * 4 + r][n * 16 + l15];
        #pragma unroll
        for (int n = 0; n < 8; ++n)
            #pragma unroll
            for (int r = 0; r < 4; ++r)
                sproj[wv][lg * 4 + r][n * 16 + l15] = accp[n][r];
    }
    __syncthreads();

    // ---- proj: reduce 4 slabs, rsqrt-normalize, write bf16 phat ----
    {
        const int row = tid >> 5;            // 0..15
        const int cq  = (tid & 31) * 4;      // 4 cols per thread
        fv4 p = {};
        #pragma unroll
        for (int w = 0; w < 4; ++w) p += *(const fv4*)&sproj[w][row][cq];
        float ssq = p[0]*p[0] + p[1]*p[1] + p[2]*p[2] + p[3]*p[3];
        #pragma unroll
        for (int m = 16; m >= 1; m >>= 1) ssq += __shfl_xor(ssq, m, 32);
        float rn = rsqrtf(ssq);
        ushort4 pk;
        pk.x = f2bf(p[0] * rn); pk.y = f2bf(p[1] * rn);
        pk.z = f2bf(p[2] * rn); pk.w = f2bf(p[3] * rn);
        *(ushort4*)&phat[(size_t)(R0 + row) * PDIM + cq] = pk;
    }

    // ---- digits: reduce 8 slabs, CE via 16-lane shuffles ----
    if (tid < 256) {
        const int drow = tid >> 4;           // 0..15
        const int dc   = tid & 15;           // cols 10..15 zero-pad
        float d = 0.0f;
        #pragma unroll
        for (int w = 0; w < 8; ++w) d += sdig[w][drow][dc];
        float dv = (dc < CDIM) ? d : -1e30f;
        float mx = dv;
        #pragma unroll
        for (int m = 8; m >= 1; m >>= 1) mx = fmaxf(mx, __shfl_xor(mx, m, 64));
        float e = (dc < CDIM) ? __expf(d - mx) : 0.0f;
        float s = e;
        #pragma unroll
        for (int m = 8; m >= 1; m >>= 1) s += __shfl_xor(s, m, 64);
        const int rowg = R0 + drow;
        const int idx  = rowg & (BDIM - 1);
        const int label = (*flag_p) ? y[2 * idx] : y[idx];
        float dl = (dc == label) ? d : 0.0f;
        #pragma unroll
        for (int m = 8; m >= 1; m >>= 1) dl += __shfl_xor(dl, m, 64);
        if (dc == 0) sce[drow] = (mx + __logf(s)) - dl;
    }
    __syncthreads();
    if (tid == 0) {
        float t = 0.0f;
        #pragma unroll
        for (int r = 0; r < 16; ++r) t += sce[r];
        atomicAdd(sup_acc, t * (1.0f / BDIM));
    }
}

// ---------------- k3: Gram row-sum via bf16 MFMA (upper-triangle tiles) ----
// LDS scatter/gather epilogue; positives need no reduction (one lane each).
__global__ __launch_bounds__(256) void k3_gram_mfma(
    const __bf16* __restrict__ ph,
    float* __restrict__ rowsum, float* __restrict__ possum)
{
    __shared__ float srow[128 * 37 + 4];   // [row][wc*16+l15], stride 37
    __shared__ float scol[128 * 9 + 4];    // [col][wr*4+lg],  stride 9
    __shared__ float spos[128];
    const int tid = threadIdx.x;

    int t = blockIdx.x;
    int ti = 0;
    while (t >= 64 - ti) { t -= 64 - ti; ++ti; }
    const int tj = ti + t;
    const int I0 = ti * 128, J0 = tj * 128;
    const bool diag    = (ti == tj);
    const bool partner = (tj == ti + 32);

    if (tid < 128) spos[tid] = 0.0f;
    __syncthreads();

    const int wid = tid >> 6, lane = tid & 63;
    const int wr = wid >> 1, wc = wid & 1;
    const int l15 = lane & 15, lg = lane >> 4;

    const int arow = I0 + wr * 64 + l15;
    const int brow = J0 + wc * 64 + l15;
    const int kb   = lg * 8;

    fv4 acc[4][4] = {};
    #pragma unroll
    for (int ks = 0; ks < 4; ++ks) {
        bfv8 a[4], b[4];
        #pragma unroll
        for (int m = 0; m < 4; ++m)
            a[m] = *(const bfv8*)(ph + (size_t)(arow + m * 16) * PDIM + ks * 32 + kb);
        #pragma unroll
        for (int n = 0; n < 4; ++n)
            b[n] = *(const bfv8*)(ph + (size_t)(brow + n * 16) * PDIM + ks * 32 + kb);
        #pragma unroll
        for (int m = 0; m < 4; ++m)
            #pragma unroll
            for (int n = 0; n < 4; ++n)
                acc[m][n] = __builtin_amdgcn_mfma_f32_16x16x32_bf16(a[m], b[n], acc[m][n], 0, 0, 0);
    }

    // epilogue: exp, diag-mask, per-lane row/col partials
    float rs_l[4][4];
    float cs_l[4] = {0, 0, 0, 0};
    #pragma unroll
    for (int m = 0; m < 4; ++m)
        #pragma unroll
        for (int r = 0; r < 4; ++r) rs_l[m][r] = 0.0f;

    #pragma unroll
    for (int m = 0; m < 4; ++m) {
        const int ribase = wr * 64 + m * 16 + lg * 4;
        #pragma unroll
        for (int n = 0; n < 4; ++n) {
            const int cj = wc * 64 + n * 16 + l15;
            #pragma unroll
            for (int r = 0; r < 4; ++r) {
                const int ri = ribase + r;
                float e = exp2f(acc[m][n][r] * EXP_SCALE);
                if (diag && ri == cj) e = 0.0f;
                rs_l[m][r] += e;
                cs_l[n] += e;
                if (partner && ri == cj) atomicAdd(&spos[ri], e);
            }
        }
    }

    // scatter partials (each slot written by exactly one lane)
    #pragma unroll
    for (int m = 0; m < 4; ++m)
        #pragma unroll
        for (int r = 0; r < 4; ++r)
            srow[(wr * 64 + m * 16 + lg * 4 + r) * 37 + wc * 16 + l15] = rs_l[m][r];
    #pragma unroll
    for (int n = 0; n < 4; ++n)
        scol[(wc * 64 + n * 16 + l15) * 9 + wr * 4 + lg] = cs_l[n];
    __syncthreads();

    // gather + one global atomic per row/col
    if (tid < 128) {
        float s = 0.0f;
        #pragma unroll
        for (int q = 0; q < 32; ++q) s += srow[tid * 37 + q];
        atomicAdd(&rowsum[I0 + tid], s);
        if (partner) atomicAdd(&possum[I0 + tid], spos[tid]);
    } else if (!diag) {
        const int col = tid - 128;
        float s = 0.0f;
        #pragma unroll
        for (int q = 0; q < 8; ++q) s += scol[col * 9 + q];
        atomicAdd(&rowsum[J0 + col], s);
        if (partner) atomicAdd(&possum[J0 + col], spos[col]);
    }
}

// ---------------- k4: final reduction (16 blocks) ----------------
__global__ __launch_bounds__(256) void k4_final(
    const float* __restrict__ rowsum, const float* __restrict__ possum,
    const float* __restrict__ sup_acc, float* __restrict__ out)
{
    __shared__ float red[4];
    const int tid = threadIdx.x;
    const int gid = blockIdx.x * 256 + tid;
    float s = 0.0f;
    #pragma unroll
    for (int i = 0; i < 2; ++i) {
        int r = gid * 2 + i;
        s += -__logf(possum[r] / rowsum[r] + EPS);
    }
    #pragma unroll
    for (int m = 32; m >= 1; m >>= 1) s += __shfl_xor(s, m, 64);
    if ((tid & 63) == 0) red[tid >> 6] = s;
    __syncthreads();
    if (tid == 0) {
        float part = (red[0] + red[1] + red[2] + red[3]) * (1.0f / TB);
        if (blockIdx.x == 0) part += LAMBDA * sup_acc[0];
        atomicAdd(out, part);
    }
}

extern "C" void kernel_launch(void* const* d_in, const int* in_sizes, int n_in,
                              void* d_out, int out_size, void* d_ws, size_t ws_size,
                              hipStream_t stream) {
    const float* xi = (const float*)d_in[1];
    const float* xj = (const float*)d_in[2];
    const int*   y  = (const int*)d_in[3];
    const float* Wp = (const float*)d_in[4];
    const float* Wc = (const float*)d_in[5];
    float* out  = (float*)d_out;

    float* ws_f   = (float*)d_ws;
    float* sup    = ws_f;
    int*   flag   = (int*)(ws_f + 1);
    float* rowsum = ws_f + 16;
    float* possum = ws_f + 16 + TB;
    unsigned short* phat_u = (unsigned short*)(ws_f + 16 + 2 * TB);
    unsigned short* WpT_u  = (unsigned short*)(ws_f + 540688);
    unsigned short* WcT_u  = (unsigned short*)(ws_f + 671760);

    k0_zero<<<(16 + 2 * TB + 255) / 256, 256, 0, stream>>>(ws_f, out);
    kf_flag<<<1, 256, 0, stream>>>(y, flag);
    kw_prep<<<(PDIM * DDIM + 16 * DDIM) / 256, 256, 0, stream>>>(Wp, Wc, WpT_u, WcT_u);
    k13_fused<<<512, 512, 0, stream>>>(xi, xj, (const __bf16*)WpT_u, (const __bf16*)WcT_u,
                                       y, flag, phat_u, sup);
    k3_gram_mfma<<<2080, 256, 0, stream>>>((const __bf16*)phat_u, rowsum, possum);
    k4_final<<<16, 256, 0, stream>>>(rowsum, possum, sup, out);
}